// Round 14
// baseline (184.996 us; speedup 1.0000x reference)
//
#include <hip/hip_runtime.h>
#include <hip/hip_bf16.h>

typedef unsigned long long u64;

static constexpr int NF = 27552;              // 2*13776 faces
static constexpr int IMGOFF = 3 * 256 * 256;  // image elements before textures
static constexpr int CAPMAX = 6144;           // per-tile list capacity (max)
static constexpr int NWAVES = 8192;           // raster waves (2048 blocks)

#define EYEZ 2.7320508075688772f   // -(EYE.z) = 1/tan(30deg)+1, fp64->fp32

// ws layout (bytes):
static constexpr size_t OFF_KEYS  = 0;        // 65536 u64
static constexpr size_t OFF_QTOT  = 524288;   // int (written by prefix_chunks)
static constexpr size_t OFF_FCNT  = 524292;   // int (zeroed by memset)
static constexpr size_t OFF_CNT   = 524352;   // 1024 int per-tile counts
static constexpr size_t OFF_CMETA = 532608;   // 98304 int4 chunk records
static constexpr size_t OFF_CF    = 2105472;  // NF*16 f32 compacted faces
static constexpr size_t OFF_CBB   = 3868800;  // NF float4 compacted bboxes
static constexpr size_t OFF_LIST  = 4309632;  // 1024*cap int

static constexpr u64 FARKEY = ((u64)0x42C80000u << 32);  // depth=100.0f, id 0

// ---------------------------------------------------------------------------
// Kernel 1 (fused): keys init + 9 tex samples/face + compacted face consts.
// Thread (f,t): recomputes the 3 projected verts from raw inputs (bit-exact
// numpy op order; 9 threads/face hit the same cache lines) and bilinear-
// samples tap t; lane t==0 additionally emits the compacted face record
// cf[p*16]: a0,a1,a2,b0,b1,b2,c0,c1,c2,ds,iz0,iz1,iz2,EMd,idbits,denmax
// (exact numpy-op-order values -> bit-identical depth path) and cbb[p].
// Front-face compaction kept (halves bin_faces' work; the fcnt atomicAdd is
// wave-aggregated by the compiler -> cheap). fcnt zeroed by host memset.
// ---------------------------------------------------------------------------
__global__ __launch_bounds__(256) void prep(
    const float* __restrict__ cam,
    const float* __restrict__ verts,
    const int* __restrict__ faces,
    const float* __restrict__ uv,
    u64* __restrict__ keys,
    float* __restrict__ cf,
    float4* __restrict__ cbb,
    int* __restrict__ fcnt,
    float* __restrict__ out_tex)
{
    int i = blockIdx.x * 256 + threadIdx.x;   // grid = 969*256 >= NF*9
    if (i < 65536) keys[i] = FARKEY;
    if (i >= NF * 9) return;
    int f = i / 9, t = i - f * 9;
    float c0 = cam[0], c1 = cam[1], c2 = cam[2];

    int vi0 = faces[f * 3 + 0], vi1 = faces[f * 3 + 1], vi2 = faces[f * 3 + 2];
    float px[3], py[3];
    px[0] = __fmul_rn(c0, __fadd_rn(verts[vi0 * 3 + 0], c1));
    py[0] = __fmul_rn(c0, __fadd_rn(verts[vi0 * 3 + 1], c2));
    px[1] = __fmul_rn(c0, __fadd_rn(verts[vi1 * 3 + 0], c1));
    py[1] = __fmul_rn(c0, __fadd_rn(verts[vi1 * 3 + 1], c2));
    px[2] = __fmul_rn(c0, __fadd_rn(verts[vi2 * 3 + 0], c1));
    py[2] = __fmul_rn(c0, __fadd_rn(verts[vi2 * 3 + 1], c2));

    // ---- texture sample for tap t ----
    const float abv[3] = {0.0f, 0.5f, 1.0f};
    int t1 = t / 3, t2 = t - t1 * 3;
    float uu = abv[t1], vv = abv[t2];
    float sx = __fadd_rn(__fadd_rn(__fmul_rn(__fsub_rn(px[0], px[2]), uu),
                                   __fmul_rn(__fsub_rn(px[1], px[2]), vv)), px[2]);
    float sy = __fadd_rn(__fadd_rn(__fmul_rn(__fsub_rn(py[0], py[2]), uu),
                                   __fmul_rn(__fsub_rn(py[1], py[2]), vv)), py[2]);
    sx = fminf(fmaxf(sx, -1.0f), 1.0f);
    sy = fminf(fmaxf(sy, -1.0f), 1.0f);
    float xg = __fmul_rn(__fmul_rn(__fadd_rn(sx, 1.0f), 0.5f), 255.0f);
    float yg = __fmul_rn(__fmul_rn(__fadd_rn(sy, 1.0f), 0.5f), 255.0f);
    float x0f = floorf(xg), y0f = floorf(yg);
    float wx = __fsub_rn(xg, x0f), wy = __fsub_rn(yg, y0f);
    int x0 = (int)x0f; x0 = x0 < 0 ? 0 : (x0 > 255 ? 255 : x0);
    int y0 = (int)y0f; y0 = y0 < 0 ? 0 : (y0 > 255 ? 255 : y0);
    int x1 = x0 + 1 > 255 ? 255 : x0 + 1;
    int y1 = y0 + 1 > 255 ? 255 : y0 + 1;
    float omwx = __fsub_rn(1.0f, wx), omwy = __fsub_rn(1.0f, wy);
    float w00 = __fmul_rn(omwx, omwy);
    float w10 = __fmul_rn(wx, omwy);
    float w01 = __fmul_rn(omwx, wy);
    float w11 = __fmul_rn(wx, wy);
    size_t tb = (size_t)f * 81 + (size_t)t1 * 27 + (size_t)t2 * 9;
#pragma unroll
    for (int c = 0; c < 3; c++) {
        const float* img = uv + c * 65536;
        float g00 = img[y0 * 256 + x0];
        float g10 = img[y0 * 256 + x1];
        float g01 = img[y1 * 256 + x0];
        float g11 = img[y1 * 256 + x1];
        float val = __fmul_rn(g00, w00);
        val = __fadd_rn(val, __fmul_rn(g10, w10));
        val = __fadd_rn(val, __fmul_rn(g01, w01));
        val = __fadd_rn(val, __fmul_rn(g11, w11));
        out_tex[tb + 0 + c] = val;   // k = 0,1,2 broadcast
        out_tex[tb + 3 + c] = val;
        out_tex[tb + 6 + c] = val;
    }

    // ---- face constants (one lane per face) ----
    if (t != 0) return;
    // replicate np look_at rounding exactly (these are 1.0 in binary FP, free)
    float z3 = __fdiv_rn(EYEZ, __fsqrt_rn(__fmul_rn(EYEZ, EYEZ)));
    float x0r = __fdiv_rn(z3, __fsqrt_rn(__fmul_rn(z3, z3)));
    float wyy = __fmul_rn(z3, x0r);
    float y1r = __fdiv_rn(wyy, __fsqrt_rn(__fmul_rn(wyy, wyy)));
    float xs[3], ys[3], zs[3];
    int vis[3] = {vi0, vi1, vi2};
#pragma unroll
    for (int k = 0; k < 3; k++) {
        xs[k] = __fmul_rn(px[k], x0r);
        ys[k] = __fmul_rn(-py[k], y1r);
        zs[k] = __fmul_rn(__fadd_rn(verts[vis[k] * 3 + 2], EYEZ), z3);
    }
    float a0 = __fsub_rn(ys[1], ys[2]);
    float a1 = __fsub_rn(ys[2], ys[0]);
    float a2 = __fsub_rn(ys[0], ys[1]);
    float b0 = __fsub_rn(xs[2], xs[1]);
    float b1 = __fsub_rn(xs[0], xs[2]);
    float b2 = __fsub_rn(xs[1], xs[0]);
    float cc0 = __fsub_rn(__fmul_rn(xs[1], ys[2]), __fmul_rn(xs[2], ys[1]));
    float cc1 = __fsub_rn(__fmul_rn(xs[2], ys[0]), __fmul_rn(xs[0], ys[2]));
    float cc2 = __fsub_rn(__fmul_rn(xs[0], ys[1]), __fmul_rn(xs[1], ys[0]));
    float det = __fadd_rn(__fadd_rn(cc0, cc1), cc2);
    if (det <= 0.0f) return;   // back faces can never be `valid` -> exact cull
    float ds  = (fabsf(det) > 1e-10f) ? det : 1e-10f;
    float z0 = (fabsf(zs[0]) > 1e-6f) ? zs[0] : 1e-6f;
    float z1 = (fabsf(zs[1]) > 1e-6f) ? zs[1] : 1e-6f;
    float z2 = (fabsf(zs[2]) > 1e-6f) ? zs[2] : 1e-6f;
    float iz0 = __fdiv_rn(1.0f, z0);
    float iz1 = __fdiv_rn(1.0f, z1);
    float iz2 = __fdiv_rn(1.0f, z2);

    int pos = atomicAdd(fcnt, 1);   // wave-aggregated by compiler
    float* q = cf + (size_t)pos * 16;
    q[0] = a0; q[1] = a1; q[2] = a2;
    q[3] = b0; q[4] = b1; q[5] = b2;
    q[6] = cc0; q[7] = cc1; q[8] = cc2;
    q[9] = ds;
    q[10] = iz0; q[11] = iz1; q[12] = iz2;
    q[13] = 2e-6f * ((iz0 + iz1) + iz2) + 1e-7f;              // EMd
    q[14] = __int_as_float(f);                                 // idbits
    q[15] = fmaxf(fmaxf(iz0, iz1), iz2) * 1.0001f + 1e-7f;     // denmax

    float4 bb;
    bb.x = fminf(fminf(xs[0], xs[1]), xs[2]) - 1e-4f;
    bb.y = fmaxf(fmaxf(xs[0], xs[1]), xs[2]) + 1e-4f;
    bb.z = fminf(fminf(ys[0], ys[1]), ys[2]) - 1e-4f;
    bb.w = fmaxf(fmaxf(ys[0], ys[1]), ys[2]) + 1e-4f;
    cbb[pos] = bb;
}

// ---------------------------------------------------------------------------
// Kernel 2: binning over COMPACTED front faces (216 groups/row, half of
// r13's 431 -- the r13 regression). SAT pass logic and mask-transpose /
// one-parallel-atomic / per-lane scatter machinery unchanged (r11,verified).
// ---------------------------------------------------------------------------
__global__ __launch_bounds__(256, 8) void bin_faces(
    const float* __restrict__ cf,
    const float4* __restrict__ cbb,
    const int* __restrict__ fcnt,
    int* __restrict__ cnt,
    int* __restrict__ list,
    int cap)
{
    __shared__ int sfid[4][64];
    const int lane = threadIdx.x & 63;
    const int wid  = threadIdx.x >> 6;
    const int w = blockIdx.x * 4 + wid;                  // 0..6911
    const int jy = w / 216;                              // tile row 0..31
    const int p  = (w - jy * 216) * 64 + lane;           // compacted face idx
    const int n = *fcnt;
    const float ylo = (float)(16 * jy + 1 - 256) * (1.0f / 256.0f);
    const float yhi = (float)(16 * jy + 15 - 256) * (1.0f / 256.0f);

    bool rv = (p < n);
    float A0 = 0, A1 = 0, A2 = 0, B0 = 0, B1 = 0, B2 = 0;
    int jx0 = 32, jx1 = -1;
    if (rv) {
        float4 bb = cbb[p];
        rv = (yhi >= bb.z) && (ylo <= bb.w);
        if (rv) {
            const float4* q = (const float4*)(cf + (size_t)p * 16);
            float4 q0 = q[0], q1 = q[1], q2 = q[2];
            float a0 = q0.x, a1 = q0.y, a2 = q0.z;
            float b0 = q0.w, b1 = q1.x, b2 = q1.y;
            float c0 = q1.z, c1 = q1.w, c2 = q2.x;
            float K0 = fmaxf(b0 * ylo, b0 * yhi) + c0;
            float K1 = fmaxf(b1 * ylo, b1 * yhi) + c1;
            float K2 = fmaxf(b2 * ylo, b2 * yhi) + c2;
            A0 = a0 * (1.0f / 16.0f);
            A1 = a1 * (1.0f / 16.0f);
            A2 = a2 * (1.0f / 16.0f);
            B0 = a0 * (((a0 > 0.f ? 15.f : 1.f) - 256.f) * (1.0f / 256.0f)) + K0;
            B1 = a1 * (((a1 > 0.f ? 15.f : 1.f) - 256.f) * (1.0f / 256.0f)) + K1;
            B2 = a2 * (((a2 > 0.f ? 15.f : 1.f) - 256.f) * (1.0f / 256.0f)) + K2;
            jx0 = (int)floorf(16.0f * bb.x + 15.0625f);
            jx1 = (int)floorf(16.0f * bb.y + 15.9375f) + 1;
            jx0 = jx0 < 0 ? 0 : jx0;
            jx1 = jx1 > 31 ? 31 : jx1;
        }
    }
    if (__ballot(rv) == 0ull) return;

    sfid[wid][lane] = p;   // stage face ids for the scatter phase
    asm volatile("s_waitcnt lgkmcnt(0)" ::: "memory");

    // (1) mask transpose: lane jx ends up holding column jx's pass mask
    u64 mymask = 0;
    for (int jx = 0; jx < 32; jx++) {
        float jf = (float)jx;
        bool pass = rv && (jx >= jx0) && (jx <= jx1) &&
                    (fmaf(jf, A0, B0) >= -1e-3f) &&
                    (fmaf(jf, A1, B1) >= -1e-3f) &&
                    (fmaf(jf, A2, B2) >= -1e-3f);
        u64 mk = __ballot(pass);
        if (lane == jx) mymask = mk;
    }

    // (2) one parallel atomic across 32 lanes (32 distinct addresses)
    int nadd = (lane < 32) ? __popcll(mymask) : 0;
    if (nadd == 0) return;
    int base = atomicAdd(&cnt[jy * 32 + lane], nadd);

    // (3) per-lane scatter: walk set bits, read ids from LDS, write list
    int* dst = list + (size_t)(jy * 32 + lane) * cap;
    u64 mm = mymask;
    int k = 0;
    while (mm) {
        int b = __builtin_ctzll(mm);
        mm &= mm - 1;
        int fid = sfid[wid][b];
        int pos = base + k;
        if (pos < cap) dst[pos] = fid;
        k++;
    }
}

// ---------------------------------------------------------------------------
// Kernel 3: closed-form parallel chunk emission (r12, verified). Band
// membership via descending counting-sort rank; within-band order is
// irrelevant (argmin is order-independent). Writes qtot itself.
// ---------------------------------------------------------------------------
__global__ __launch_bounds__(1024) void prefix_chunks(
    const int* __restrict__ cnt,
    int cap,
    int4* __restrict__ cmeta,
    int* __restrict__ qtot)
{
    __shared__ int hist[128];
    __shared__ int sbase[128];     // #{c' > c} = sort base = band size B_c
    __shared__ int bstart[128];    // bandstart[j]
    __shared__ int scat[128];      // mutable scatter counters
    const int t = threadIdx.x;     // tile id, 0..1023
    int len = cnt[t]; if (len > cap) len = cap;
    const int cch = (len + 63) >> 6;   // chunk count, 0..96
    if (t < 128) hist[t] = 0;
    __syncthreads();
    atomicAdd(&hist[cch], 1);
    __syncthreads();
    if (t == 0) {
        sbase[97] = 0;
        for (int c = 96; c >= 0; c--) sbase[c] = sbase[c + 1] + hist[c + 1];
        int acc = 0;
        for (int j = 0; j <= 96; j++) { bstart[j] = acc; acc += sbase[j]; scat[j] = sbase[j]; }
        *qtot = acc;
    }
    __syncthreads();
    int s = atomicAdd(&scat[cch], 1);   // descending sort rank
    for (int j = 0; j < cch; j++) {
        int m = len - j * 64; if (m > 64) m = 64;
        int4 rec; rec.x = t * cap + j * 64; rec.y = m; rec.z = t; rec.w = 0;
        cmeta[bstart[j] + s] = rec;
    }
}

// ---------------------------------------------------------------------------
// Kernel 4: depth argmin, static round-robin over chunks (r12, verified).
// denmax early-skip + slim exact-t filter + bit-exact numpy path.
// ---------------------------------------------------------------------------
__global__ __launch_bounds__(256, 8) void raster_score(
    const float* __restrict__ cf,
    const int* __restrict__ list,
    const int4* __restrict__ cmeta,
    const int* __restrict__ qtot,
    u64* __restrict__ keys)
{
    __shared__ __align__(16) float sface[4][1216];   // 4864 B per wave
    const int lane = threadIdx.x & 63;
    const int wid  = threadIdx.x >> 6;
    float* sf = sface[wid];
    const int total = *qtot;

    int c = blockIdx.x * 4 + wid;     // global wave id = first chunk
    if (c >= total) return;
    int4 mt = cmeta[c];

    for (;;) {
        const int4 cur = mt;
        const int cn = c + NWAVES;
        const bool hasnext = (cn < total);
        if (hasnext) mt = cmeta[cn];   // prefetch next record (independent)

        const int tile = cur.z;
        const int m = cur.y;
        const int tx = tile & 31, ty = tile >> 5;
        const int pxi = tx * 8 + (lane & 7), pyi = ty * 8 + (lane >> 3);
        const int pix = pyi * 256 + pxi;
        const float xp = (float)(2 * pxi + 1 - 256) * (1.0f / 256.0f);  // exact
        const float yp = (float)(2 * pyi + 1 - 256) * (1.0f / 256.0f);

        // gather one 64B block per entry (lanes 0..m-1)
        float4 g0, g1, g2, g3;
        bool cv = (lane < m);
        if (cv) {
            int cid = list[cur.x + lane];
            const float4* p4 = (const float4*)(cf + (size_t)cid * 16);
            g0 = p4[0]; g1 = p4[1]; g2 = p4[2]; g3 = p4[3];
        }
        u64 sk = keys[pix];   // seed gate (issues alongside gather)
        if (cv) {
            // g2 = (c2, ds, iz0, iz1); g3 = (iz2, EMd, idbits, denmax)
            float rds = __builtin_amdgcn_rcpf(g2.y);
            float u0 = g2.z * rds, u1 = g2.w * rds, u2 = g3.x * rds;
            *(float4*)(sf +   0 + lane * 4) = g0;                              // A0
            *(float4*)(sf + 256 + lane * 4) = g1;                              // A1
            *(float4*)(sf + 512 + lane * 4) = make_float4(g2.x, u0, u1, u2);   // A2
            *(float2*)(sf + 768 + lane * 2) = make_float2(g3.w, g3.y);         // B
            *(float4*)(sf + 896 + lane * 4) = make_float4(g2.y, g2.z, g2.w, g3.x); // C
            sf[1152 + lane] = g3.z;                                            // id
        }
        float bfv = __uint_as_float((unsigned)(sk >> 32));
        float thr = fmaxf(0.9935f * __builtin_amdgcn_rcpf(bfv) - 1e-4f, 0.0098f);
        u64 best = FARKEY;
        asm volatile("s_waitcnt lgkmcnt(0)" ::: "memory");

        for (int j = 0; j < m; j++) {
            float2 db = *(const float2*)(sf + 768 + 2 * j);  // denmax, EMd
            if (!__any(db.x >= thr)) continue;               // provable reject
            float4 q0 = *(const float4*)(sf +   0 + 4 * j);  // a0,a1,a2,b0
            float4 q1 = *(const float4*)(sf + 256 + 4 * j);  // b1,b2,c0,c1
            float4 q2 = *(const float4*)(sf + 512 + 4 * j);  // c2,u0,u1,u2
            // exact t's (numpy op order) -- shared by filter and exact path
            float t0 = __fadd_rn(__fadd_rn(__fmul_rn(xp, q0.x), __fmul_rn(yp, q0.w)), q1.z);
            float t1 = __fadd_rn(__fadd_rn(__fmul_rn(xp, q0.y), __fmul_rn(yp, q1.x)), q1.w);
            float t2 = __fadd_rn(__fadd_rn(__fmul_rn(xp, q0.z), __fmul_rn(yp, q1.y)), q2.x);
            float tmin = fminf(fminf(t0, t1), t2);
            float dena = fmaf(t0, q2.y, fmaf(t1, q2.z, fmaf(t2, q2.w, db.y)));
            bool pass = (tmin >= 0.0f) && (dena >= thr);
            if (__any(pass)) {
                float4 cc = *(const float4*)(sf + 896 + 4 * j);  // ds,iz0,iz1,iz2
                float idb = sf[1152 + j];
                // bit-exact numpy path (t's reused)
                bool in = !(t0 < 0.0f) && !(t1 < 0.0f) && !(t2 < 0.0f);
                float w0 = __fdiv_rn(t0, cc.x);
                float w1 = __fdiv_rn(t1, cc.x);
                float w2 = __fdiv_rn(t2, cc.x);
                in = in && !(w0 > 1.0f) && !(w1 > 1.0f) && !(w2 > 1.0f);
                float den = __fmul_rn(w0, cc.y);
                den = __fadd_rn(den, __fmul_rn(w1, cc.z));
                den = __fadd_rn(den, __fmul_rn(w2, cc.w));
                if (in && den > 1e-8f) {
                    float zp = __fdiv_rn(1.0f, den);
                    if (zp > 0.1f && zp < 100.0f) {
                        u64 key = ((u64)__float_as_uint(zp) << 32)
                                | (u64)(unsigned)__float_as_int(idb);
                        if (key < best) {
                            best = key;
                            float b2f = __uint_as_float((unsigned)(best >> 32));
                            thr = fmaxf(thr,
                                0.9935f * __builtin_amdgcn_rcpf(b2f) - 1e-4f);
                        }
                    }
                }
            }
        }
        if (best != FARKEY)
            atomicMin(&keys[pix], best);
        if (!hasnext) return;
        c = cn;
    }
}

// ---------------------------------------------------------------------------
// Kernel 5: per-pixel epilogue — recompute the winner face's constants from
// the raw inputs (bit-exact prep replica), exact barycentrics, then
// trilinear-sample the face texture (numpy op order).
// ---------------------------------------------------------------------------
__global__ __launch_bounds__(256) void epilogue(
    const u64* __restrict__ keys,
    const float* __restrict__ cam,
    const float* __restrict__ verts,
    const int* __restrict__ faces,
    const float* __restrict__ tex,   // d_out + IMGOFF, from prep
    float* __restrict__ out_img)
{
    int pix = blockIdx.x * 256 + threadIdx.x;   // 65536
    int xo = pix & 255, yo = pix >> 8;
    const float xp = (float)(2 * xo + 1 - 256) * (1.0f / 256.0f);
    const float yp = (float)(2 * yo + 1 - 256) * (1.0f / 256.0f);
    u64 m = keys[pix];
    float depth = __uint_as_float((unsigned)(m >> 32));
    float col0 = 0.f, col1 = 0.f, col2 = 0.f;
    if (depth < 100.0f) {
        int fidx = (int)(unsigned)(m & 0xFFFFFFFFu);
        float c0 = cam[0], c1 = cam[1], c2 = cam[2];
        float z3 = __fdiv_rn(EYEZ, __fsqrt_rn(__fmul_rn(EYEZ, EYEZ)));
        float x0r = __fdiv_rn(z3, __fsqrt_rn(__fmul_rn(z3, z3)));
        float wyy = __fmul_rn(z3, x0r);
        float y1r = __fdiv_rn(wyy, __fsqrt_rn(__fmul_rn(wyy, wyy)));
        float xs[3], ys[3], zs[3];
#pragma unroll
        for (int i = 0; i < 3; i++) {
            int vi = faces[fidx * 3 + i];
            float vx = verts[vi * 3 + 0];
            float vy = verts[vi * 3 + 1];
            float vz = verts[vi * 3 + 2];
            float px = __fmul_rn(c0, __fadd_rn(vx, c1));
            float py = __fmul_rn(c0, __fadd_rn(vy, c2));
            xs[i] = __fmul_rn(px, x0r);
            ys[i] = __fmul_rn(-py, y1r);
            zs[i] = __fmul_rn(__fadd_rn(vz, EYEZ), z3);
        }
        float a0 = __fsub_rn(ys[1], ys[2]);
        float a1 = __fsub_rn(ys[2], ys[0]);
        float a2 = __fsub_rn(ys[0], ys[1]);
        float b0 = __fsub_rn(xs[2], xs[1]);
        float b1 = __fsub_rn(xs[0], xs[2]);
        float b2 = __fsub_rn(xs[1], xs[0]);
        float cc0 = __fsub_rn(__fmul_rn(xs[1], ys[2]), __fmul_rn(xs[2], ys[1]));
        float cc1 = __fsub_rn(__fmul_rn(xs[2], ys[0]), __fmul_rn(xs[0], ys[2]));
        float cc2 = __fsub_rn(__fmul_rn(xs[0], ys[1]), __fmul_rn(xs[1], ys[0]));
        float det = __fadd_rn(__fadd_rn(cc0, cc1), cc2);
        float dsf = (fabsf(det) > 1e-10f) ? det : 1e-10f;
        float z0 = (fabsf(zs[0]) > 1e-6f) ? zs[0] : 1e-6f;
        float z1 = (fabsf(zs[1]) > 1e-6f) ? zs[1] : 1e-6f;
        float z2 = (fabsf(zs[2]) > 1e-6f) ? zs[2] : 1e-6f;

        float t0 = __fadd_rn(__fadd_rn(__fmul_rn(xp, a0), __fmul_rn(yp, b0)), cc0);
        float t1 = __fadd_rn(__fadd_rn(__fmul_rn(xp, a1), __fmul_rn(yp, b1)), cc1);
        float t2 = __fadd_rn(__fadd_rn(__fmul_rn(xp, a2), __fmul_rn(yp, b2)), cc2);
        float w0 = __fdiv_rn(t0, dsf), w1 = __fdiv_rn(t1, dsf), w2 = __fdiv_rn(t2, dsf);
        float wc0 = __fdiv_rn(w0, z0);
        float wc1 = __fdiv_rn(w1, z1);
        float wc2 = __fdiv_rn(w2, z2);
        float ssum = __fadd_rn(__fadd_rn(wc0, wc1), wc2);
        float dnm = fmaxf(ssum, 1e-8f);
        wc0 = __fdiv_rn(wc0, dnm); wc1 = __fdiv_rn(wc1, dnm); wc2 = __fdiv_rn(wc2, dnm);
        float pos0 = __fmul_rn(fminf(fmaxf(wc0, 0.f), 1.f), 2.0f);
        float pos1 = __fmul_rn(fminf(fmaxf(wc1, 0.f), 1.f), 2.0f);
        float pos2 = __fmul_rn(fminf(fmaxf(wc2, 0.f), 1.f), 2.0f);
        float lf0 = fminf(fmaxf(floorf(pos0), 0.f), 2.f);
        float lf1 = fminf(fmaxf(floorf(pos1), 0.f), 2.f);
        float lf2 = fminf(fmaxf(floorf(pos2), 0.f), 2.f);
        float fr0 = __fsub_rn(pos0, lf0), fr1 = __fsub_rn(pos1, lf1), fr2 = __fsub_rn(pos2, lf2);
        int lo0 = (int)lf0, lo1 = (int)lf1;
        int hi0 = lo0 + 1 > 2 ? 2 : lo0 + 1;
        int hi1 = lo1 + 1 > 2 ? 2 : lo1 + 1;
        const float* tbase = tex + (size_t)fidx * 81;
#pragma unroll
        for (int bits = 0; bits < 8; bits++) {
            int u0 = bits & 1, u1 = (bits >> 1) & 1, u2 = (bits >> 2) & 1;
            int i0 = u0 ? hi0 : lo0;
            int i1 = u1 ? hi1 : lo1;
            float e0 = u0 ? fr0 : __fsub_rn(1.0f, fr0);
            float e1 = u1 ? fr1 : __fsub_rn(1.0f, fr1);
            float e2 = u2 ? fr2 : __fsub_rn(1.0f, fr2);
            float wgt = __fmul_rn(__fmul_rn(e0, e1), e2);
            const float* tp = tbase + (size_t)i0 * 27 + (size_t)i1 * 9;  // k broadcast
            col0 = __fadd_rn(col0, __fmul_rn(wgt, tp[0]));
            col1 = __fadd_rn(col1, __fmul_rn(wgt, tp[1]));
            col2 = __fadd_rn(col2, __fmul_rn(wgt, tp[2]));
        }
    }
    out_img[pix]          = col0;
    out_img[65536 + pix]  = col1;
    out_img[131072 + pix] = col2;
}

extern "C" void kernel_launch(void* const* d_in, const int* in_sizes, int n_in,
                              void* d_out, int out_size, void* d_ws, size_t ws_size,
                              hipStream_t stream) {
    const float* cam   = (const float*)d_in[0];
    const float* verts = (const float*)d_in[1];
    const float* uv    = (const float*)d_in[2];
    const int*   faces = (const int*)d_in[3];
    float* out = (float*)d_out;

    char* ws = (char*)d_ws;
    u64*    keys  = (u64*)(ws + OFF_KEYS);
    int*    qtot  = (int*)(ws + OFF_QTOT);
    int*    fcnt  = (int*)(ws + OFF_FCNT);
    int*    cntp  = (int*)(ws + OFF_CNT);
    int4*   cmeta = (int4*)(ws + OFF_CMETA);
    float*  cf    = (float*)(ws + OFF_CF);
    float4* cbb   = (float4*)(ws + OFF_CBB);
    int*    list  = (int*)(ws + OFF_LIST);

    int cap = CAPMAX;
    if (ws_size > OFF_LIST) {
        size_t avail = (ws_size - OFF_LIST) / (1024 * sizeof(int));
        if ((size_t)cap > avail) cap = (int)avail;
    } else {
        cap = 0;
    }

    float* out_img = out;            // 3*256*256
    float* out_tex = out + IMGOFF;   // NF*81

    // zero fcnt + per-tile cnt (graph-capture-safe async memset)
    hipMemsetAsync(ws + OFF_QTOT, 0, (OFF_CNT + 4096) - OFF_QTOT, stream);

    hipLaunchKernelGGL(prep, dim3((NF * 9 + 255) / 256), dim3(256), 0, stream,
                       cam, verts, faces, uv, keys, cf, cbb, fcnt, out_tex);
    hipLaunchKernelGGL(bin_faces, dim3(1728), dim3(256), 0, stream,
                       cf, cbb, fcnt, cntp, list, cap);
    hipLaunchKernelGGL(prefix_chunks, dim3(1), dim3(1024), 0, stream,
                       cntp, cap, cmeta, qtot);
    hipLaunchKernelGGL(raster_score, dim3(NWAVES / 4), dim3(256), 0, stream,
                       cf, list, cmeta, qtot, keys);
    hipLaunchKernelGGL(epilogue, dim3(256), dim3(256), 0, stream,
                       keys, cam, verts, faces, out_tex, out_img);
}

// Round 15
// 149.576 us; speedup vs baseline: 1.2368x; 1.2368x over previous
//
#include <hip/hip_runtime.h>
#include <hip/hip_bf16.h>

typedef unsigned long long u64;

static constexpr int NF = 27552;              // 2*13776 faces
static constexpr int IMGOFF = 3 * 256 * 256;  // image elements before textures
static constexpr int CAPMAX = 6144;           // per-tile list capacity (max)
static constexpr int NWAVES = 8192;           // raster waves (2048 blocks)

#define EYEZ 2.7320508075688772f   // -(EYE.z) = 1/tan(30deg)+1, fp64->fp32

// ws layout (bytes):
static constexpr size_t OFF_KEYS  = 0;        // 65536 u64
static constexpr size_t OFF_QTOT  = 524288;   // int (written by prefix_chunks)
static constexpr size_t OFF_FCNT  = 524292;   // int (zeroed by memset)
static constexpr size_t OFF_CNT   = 524352;   // 1024 int per-tile counts
static constexpr size_t OFF_CMETA = 532608;   // 98304 int4 chunk records
static constexpr size_t OFF_CF    = 2105472;  // NF*16 f32 compacted faces
static constexpr size_t OFF_CBB   = 3868800;  // NF float4 compacted bboxes
static constexpr size_t OFF_LIST  = 4309632;  // 1024*cap int

static constexpr u64 FARKEY = ((u64)0x42C80000u << 32);  // depth=100.0f, id 0

// ---------------------------------------------------------------------------
// Kernel 1 (fused): keys init + 9 tex samples/face + compacted face consts.
// Tex: thread i handles tap t=i%9 of face i/9 (recomputes projected verts
// from raw inputs, bit-exact numpy op order).
// Consts: thread i<NF handles face i -- DECOUPLED from the tex index so the
// wave-aggregated fcnt atomicAdd runs in only ~431 waves (r14 keyed it on
// t==0 across 3876 waves -> ~3876 serialized same-address RMWs = 30us;
// this was the r14 regression).
// cf[p*16]: a0,a1,a2,b0,b1,b2,c0,c1,c2,ds,iz0,iz1,iz2,EMd,idbits,denmax
// (exact numpy-op-order values -> bit-identical depth path); cbb[p] = bbox.
// fcnt zeroed by host memset.
// ---------------------------------------------------------------------------
__global__ __launch_bounds__(256) void prep(
    const float* __restrict__ cam,
    const float* __restrict__ verts,
    const int* __restrict__ faces,
    const float* __restrict__ uv,
    u64* __restrict__ keys,
    float* __restrict__ cf,
    float4* __restrict__ cbb,
    int* __restrict__ fcnt,
    float* __restrict__ out_tex)
{
    int i = blockIdx.x * 256 + threadIdx.x;   // grid = 969*256 >= NF*9
    if (i < 65536) keys[i] = FARKEY;
    float c0 = cam[0], c1 = cam[1], c2 = cam[2];

    // ---- face constants + compaction: face index = i (first 431 waves) ----
    if (i < NF) {
        int f = i;
        int vi0 = faces[f * 3 + 0], vi1 = faces[f * 3 + 1], vi2 = faces[f * 3 + 2];
        // replicate np look_at rounding exactly (1.0 in binary FP, free)
        float z3 = __fdiv_rn(EYEZ, __fsqrt_rn(__fmul_rn(EYEZ, EYEZ)));
        float x0r = __fdiv_rn(z3, __fsqrt_rn(__fmul_rn(z3, z3)));
        float wyy = __fmul_rn(z3, x0r);
        float y1r = __fdiv_rn(wyy, __fsqrt_rn(__fmul_rn(wyy, wyy)));
        float xs[3], ys[3], zs[3];
        int vis[3] = {vi0, vi1, vi2};
#pragma unroll
        for (int k = 0; k < 3; k++) {
            float px = __fmul_rn(c0, __fadd_rn(verts[vis[k] * 3 + 0], c1));
            float py = __fmul_rn(c0, __fadd_rn(verts[vis[k] * 3 + 1], c2));
            xs[k] = __fmul_rn(px, x0r);
            ys[k] = __fmul_rn(-py, y1r);
            zs[k] = __fmul_rn(__fadd_rn(verts[vis[k] * 3 + 2], EYEZ), z3);
        }
        float a0 = __fsub_rn(ys[1], ys[2]);
        float a1 = __fsub_rn(ys[2], ys[0]);
        float a2 = __fsub_rn(ys[0], ys[1]);
        float b0 = __fsub_rn(xs[2], xs[1]);
        float b1 = __fsub_rn(xs[0], xs[2]);
        float b2 = __fsub_rn(xs[1], xs[0]);
        float cc0 = __fsub_rn(__fmul_rn(xs[1], ys[2]), __fmul_rn(xs[2], ys[1]));
        float cc1 = __fsub_rn(__fmul_rn(xs[2], ys[0]), __fmul_rn(xs[0], ys[2]));
        float cc2 = __fsub_rn(__fmul_rn(xs[0], ys[1]), __fmul_rn(xs[1], ys[0]));
        float det = __fadd_rn(__fadd_rn(cc0, cc1), cc2);
        if (det > 0.0f) {   // back faces can never be `valid` -> exact cull
            float ds  = (fabsf(det) > 1e-10f) ? det : 1e-10f;
            float z0 = (fabsf(zs[0]) > 1e-6f) ? zs[0] : 1e-6f;
            float z1 = (fabsf(zs[1]) > 1e-6f) ? zs[1] : 1e-6f;
            float z2 = (fabsf(zs[2]) > 1e-6f) ? zs[2] : 1e-6f;
            float iz0 = __fdiv_rn(1.0f, z0);
            float iz1 = __fdiv_rn(1.0f, z1);
            float iz2 = __fdiv_rn(1.0f, z2);
            int pos = atomicAdd(fcnt, 1);   // wave-aggregated, ~431 waves
            float* q = cf + (size_t)pos * 16;
            q[0] = a0; q[1] = a1; q[2] = a2;
            q[3] = b0; q[4] = b1; q[5] = b2;
            q[6] = cc0; q[7] = cc1; q[8] = cc2;
            q[9] = ds;
            q[10] = iz0; q[11] = iz1; q[12] = iz2;
            q[13] = 2e-6f * ((iz0 + iz1) + iz2) + 1e-7f;              // EMd
            q[14] = __int_as_float(f);                                 // idbits
            q[15] = fmaxf(fmaxf(iz0, iz1), iz2) * 1.0001f + 1e-7f;     // denmax
            float4 bb;
            bb.x = fminf(fminf(xs[0], xs[1]), xs[2]) - 1e-4f;
            bb.y = fmaxf(fmaxf(xs[0], xs[1]), xs[2]) + 1e-4f;
            bb.z = fminf(fminf(ys[0], ys[1]), ys[2]) - 1e-4f;
            bb.w = fmaxf(fmaxf(ys[0], ys[1]), ys[2]) + 1e-4f;
            cbb[pos] = bb;
        }
    }

    // ---- texture sample: tap t of face i/9 ----
    if (i >= NF * 9) return;
    int f = i / 9, t = i - f * 9;
    int vi0 = faces[f * 3 + 0], vi1 = faces[f * 3 + 1], vi2 = faces[f * 3 + 2];
    float px[3], py[3];
    px[0] = __fmul_rn(c0, __fadd_rn(verts[vi0 * 3 + 0], c1));
    py[0] = __fmul_rn(c0, __fadd_rn(verts[vi0 * 3 + 1], c2));
    px[1] = __fmul_rn(c0, __fadd_rn(verts[vi1 * 3 + 0], c1));
    py[1] = __fmul_rn(c0, __fadd_rn(verts[vi1 * 3 + 1], c2));
    px[2] = __fmul_rn(c0, __fadd_rn(verts[vi2 * 3 + 0], c1));
    py[2] = __fmul_rn(c0, __fadd_rn(verts[vi2 * 3 + 1], c2));

    const float abv[3] = {0.0f, 0.5f, 1.0f};
    int t1 = t / 3, t2 = t - t1 * 3;
    float uu = abv[t1], vv = abv[t2];
    float sx = __fadd_rn(__fadd_rn(__fmul_rn(__fsub_rn(px[0], px[2]), uu),
                                   __fmul_rn(__fsub_rn(px[1], px[2]), vv)), px[2]);
    float sy = __fadd_rn(__fadd_rn(__fmul_rn(__fsub_rn(py[0], py[2]), uu),
                                   __fmul_rn(__fsub_rn(py[1], py[2]), vv)), py[2]);
    sx = fminf(fmaxf(sx, -1.0f), 1.0f);
    sy = fminf(fmaxf(sy, -1.0f), 1.0f);
    float xg = __fmul_rn(__fmul_rn(__fadd_rn(sx, 1.0f), 0.5f), 255.0f);
    float yg = __fmul_rn(__fmul_rn(__fadd_rn(sy, 1.0f), 0.5f), 255.0f);
    float x0f = floorf(xg), y0f = floorf(yg);
    float wx = __fsub_rn(xg, x0f), wy = __fsub_rn(yg, y0f);
    int x0 = (int)x0f; x0 = x0 < 0 ? 0 : (x0 > 255 ? 255 : x0);
    int y0 = (int)y0f; y0 = y0 < 0 ? 0 : (y0 > 255 ? 255 : y0);
    int x1 = x0 + 1 > 255 ? 255 : x0 + 1;
    int y1 = y0 + 1 > 255 ? 255 : y0 + 1;
    float omwx = __fsub_rn(1.0f, wx), omwy = __fsub_rn(1.0f, wy);
    float w00 = __fmul_rn(omwx, omwy);
    float w10 = __fmul_rn(wx, omwy);
    float w01 = __fmul_rn(omwx, wy);
    float w11 = __fmul_rn(wx, wy);
    size_t tb = (size_t)f * 81 + (size_t)t1 * 27 + (size_t)t2 * 9;
#pragma unroll
    for (int c = 0; c < 3; c++) {
        const float* img = uv + c * 65536;
        float g00 = img[y0 * 256 + x0];
        float g10 = img[y0 * 256 + x1];
        float g01 = img[y1 * 256 + x0];
        float g11 = img[y1 * 256 + x1];
        float val = __fmul_rn(g00, w00);
        val = __fadd_rn(val, __fmul_rn(g10, w10));
        val = __fadd_rn(val, __fmul_rn(g01, w01));
        val = __fadd_rn(val, __fmul_rn(g11, w11));
        out_tex[tb + 0 + c] = val;   // k = 0,1,2 broadcast
        out_tex[tb + 3 + c] = val;
        out_tex[tb + 6 + c] = val;
    }
}

// ---------------------------------------------------------------------------
// Kernel 2: binning over COMPACTED front faces (216 groups/row). SAT pass
// logic + mask-transpose / one-parallel-atomic / scatter (r11, verified).
// ---------------------------------------------------------------------------
__global__ __launch_bounds__(256, 8) void bin_faces(
    const float* __restrict__ cf,
    const float4* __restrict__ cbb,
    const int* __restrict__ fcnt,
    int* __restrict__ cnt,
    int* __restrict__ list,
    int cap)
{
    __shared__ int sfid[4][64];
    const int lane = threadIdx.x & 63;
    const int wid  = threadIdx.x >> 6;
    const int w = blockIdx.x * 4 + wid;                  // 0..6911
    const int jy = w / 216;                              // tile row 0..31
    const int p  = (w - jy * 216) * 64 + lane;           // compacted face idx
    const int n = *fcnt;
    const float ylo = (float)(16 * jy + 1 - 256) * (1.0f / 256.0f);
    const float yhi = (float)(16 * jy + 15 - 256) * (1.0f / 256.0f);

    bool rv = (p < n);
    float A0 = 0, A1 = 0, A2 = 0, B0 = 0, B1 = 0, B2 = 0;
    int jx0 = 32, jx1 = -1;
    if (rv) {
        float4 bb = cbb[p];
        rv = (yhi >= bb.z) && (ylo <= bb.w);
        if (rv) {
            const float4* q = (const float4*)(cf + (size_t)p * 16);
            float4 q0 = q[0], q1 = q[1], q2 = q[2];
            float a0 = q0.x, a1 = q0.y, a2 = q0.z;
            float b0 = q0.w, b1 = q1.x, b2 = q1.y;
            float c0 = q1.z, c1 = q1.w, c2 = q2.x;
            float K0 = fmaxf(b0 * ylo, b0 * yhi) + c0;
            float K1 = fmaxf(b1 * ylo, b1 * yhi) + c1;
            float K2 = fmaxf(b2 * ylo, b2 * yhi) + c2;
            A0 = a0 * (1.0f / 16.0f);
            A1 = a1 * (1.0f / 16.0f);
            A2 = a2 * (1.0f / 16.0f);
            B0 = a0 * (((a0 > 0.f ? 15.f : 1.f) - 256.f) * (1.0f / 256.0f)) + K0;
            B1 = a1 * (((a1 > 0.f ? 15.f : 1.f) - 256.f) * (1.0f / 256.0f)) + K1;
            B2 = a2 * (((a2 > 0.f ? 15.f : 1.f) - 256.f) * (1.0f / 256.0f)) + K2;
            jx0 = (int)floorf(16.0f * bb.x + 15.0625f);
            jx1 = (int)floorf(16.0f * bb.y + 15.9375f) + 1;
            jx0 = jx0 < 0 ? 0 : jx0;
            jx1 = jx1 > 31 ? 31 : jx1;
        }
    }
    if (__ballot(rv) == 0ull) return;

    sfid[wid][lane] = p;   // stage face ids for the scatter phase
    asm volatile("s_waitcnt lgkmcnt(0)" ::: "memory");

    // (1) mask transpose: lane jx ends up holding column jx's pass mask
    u64 mymask = 0;
    for (int jx = 0; jx < 32; jx++) {
        float jf = (float)jx;
        bool pass = rv && (jx >= jx0) && (jx <= jx1) &&
                    (fmaf(jf, A0, B0) >= -1e-3f) &&
                    (fmaf(jf, A1, B1) >= -1e-3f) &&
                    (fmaf(jf, A2, B2) >= -1e-3f);
        u64 mk = __ballot(pass);
        if (lane == jx) mymask = mk;
    }

    // (2) one parallel atomic across 32 lanes (32 distinct addresses)
    int nadd = (lane < 32) ? __popcll(mymask) : 0;
    if (nadd == 0) return;
    int base = atomicAdd(&cnt[jy * 32 + lane], nadd);

    // (3) per-lane scatter: walk set bits, read ids from LDS, write list
    int* dst = list + (size_t)(jy * 32 + lane) * cap;
    u64 mm = mymask;
    int k = 0;
    while (mm) {
        int b = __builtin_ctzll(mm);
        mm &= mm - 1;
        int fid = sfid[wid][b];
        int pos = base + k;
        if (pos < cap) dst[pos] = fid;
        k++;
    }
}

// ---------------------------------------------------------------------------
// Kernel 3: closed-form parallel chunk emission (r12, verified).
// ---------------------------------------------------------------------------
__global__ __launch_bounds__(1024) void prefix_chunks(
    const int* __restrict__ cnt,
    int cap,
    int4* __restrict__ cmeta,
    int* __restrict__ qtot)
{
    __shared__ int hist[128];
    __shared__ int sbase[128];
    __shared__ int bstart[128];
    __shared__ int scat[128];
    const int t = threadIdx.x;     // tile id, 0..1023
    int len = cnt[t]; if (len > cap) len = cap;
    const int cch = (len + 63) >> 6;   // chunk count, 0..96
    if (t < 128) hist[t] = 0;
    __syncthreads();
    atomicAdd(&hist[cch], 1);
    __syncthreads();
    if (t == 0) {
        sbase[97] = 0;
        for (int c = 96; c >= 0; c--) sbase[c] = sbase[c + 1] + hist[c + 1];
        int acc = 0;
        for (int j = 0; j <= 96; j++) { bstart[j] = acc; acc += sbase[j]; scat[j] = sbase[j]; }
        *qtot = acc;
    }
    __syncthreads();
    int s = atomicAdd(&scat[cch], 1);   // descending sort rank
    for (int j = 0; j < cch; j++) {
        int m = len - j * 64; if (m > 64) m = 64;
        int4 rec; rec.x = t * cap + j * 64; rec.y = m; rec.z = t; rec.w = 0;
        cmeta[bstart[j] + s] = rec;
    }
}

// ---------------------------------------------------------------------------
// Kernel 4: depth argmin, static round-robin over chunks (r12, verified).
// denmax early-skip + slim exact-t filter + bit-exact numpy path.
// ---------------------------------------------------------------------------
__global__ __launch_bounds__(256, 8) void raster_score(
    const float* __restrict__ cf,
    const int* __restrict__ list,
    const int4* __restrict__ cmeta,
    const int* __restrict__ qtot,
    u64* __restrict__ keys)
{
    __shared__ __align__(16) float sface[4][1216];   // 4864 B per wave
    const int lane = threadIdx.x & 63;
    const int wid  = threadIdx.x >> 6;
    float* sf = sface[wid];
    const int total = *qtot;

    int c = blockIdx.x * 4 + wid;     // global wave id = first chunk
    if (c >= total) return;
    int4 mt = cmeta[c];

    for (;;) {
        const int4 cur = mt;
        const int cn = c + NWAVES;
        const bool hasnext = (cn < total);
        if (hasnext) mt = cmeta[cn];   // prefetch next record (independent)

        const int tile = cur.z;
        const int m = cur.y;
        const int tx = tile & 31, ty = tile >> 5;
        const int pxi = tx * 8 + (lane & 7), pyi = ty * 8 + (lane >> 3);
        const int pix = pyi * 256 + pxi;
        const float xp = (float)(2 * pxi + 1 - 256) * (1.0f / 256.0f);  // exact
        const float yp = (float)(2 * pyi + 1 - 256) * (1.0f / 256.0f);

        // gather one 64B block per entry (lanes 0..m-1)
        float4 g0, g1, g2, g3;
        bool cv = (lane < m);
        if (cv) {
            int cid = list[cur.x + lane];
            const float4* p4 = (const float4*)(cf + (size_t)cid * 16);
            g0 = p4[0]; g1 = p4[1]; g2 = p4[2]; g3 = p4[3];
        }
        u64 sk = keys[pix];   // seed gate (issues alongside gather)
        if (cv) {
            // g2 = (c2, ds, iz0, iz1); g3 = (iz2, EMd, idbits, denmax)
            float rds = __builtin_amdgcn_rcpf(g2.y);
            float u0 = g2.z * rds, u1 = g2.w * rds, u2 = g3.x * rds;
            *(float4*)(sf +   0 + lane * 4) = g0;                              // A0
            *(float4*)(sf + 256 + lane * 4) = g1;                              // A1
            *(float4*)(sf + 512 + lane * 4) = make_float4(g2.x, u0, u1, u2);   // A2
            *(float2*)(sf + 768 + lane * 2) = make_float2(g3.w, g3.y);         // B
            *(float4*)(sf + 896 + lane * 4) = make_float4(g2.y, g2.z, g2.w, g3.x); // C
            sf[1152 + lane] = g3.z;                                            // id
        }
        float bfv = __uint_as_float((unsigned)(sk >> 32));
        float thr = fmaxf(0.9935f * __builtin_amdgcn_rcpf(bfv) - 1e-4f, 0.0098f);
        u64 best = FARKEY;
        asm volatile("s_waitcnt lgkmcnt(0)" ::: "memory");

        for (int j = 0; j < m; j++) {
            float2 db = *(const float2*)(sf + 768 + 2 * j);  // denmax, EMd
            if (!__any(db.x >= thr)) continue;               // provable reject
            float4 q0 = *(const float4*)(sf +   0 + 4 * j);  // a0,a1,a2,b0
            float4 q1 = *(const float4*)(sf + 256 + 4 * j);  // b1,b2,c0,c1
            float4 q2 = *(const float4*)(sf + 512 + 4 * j);  // c2,u0,u1,u2
            // exact t's (numpy op order) -- shared by filter and exact path
            float t0 = __fadd_rn(__fadd_rn(__fmul_rn(xp, q0.x), __fmul_rn(yp, q0.w)), q1.z);
            float t1 = __fadd_rn(__fadd_rn(__fmul_rn(xp, q0.y), __fmul_rn(yp, q1.x)), q1.w);
            float t2 = __fadd_rn(__fadd_rn(__fmul_rn(xp, q0.z), __fmul_rn(yp, q1.y)), q2.x);
            float tmin = fminf(fminf(t0, t1), t2);
            float dena = fmaf(t0, q2.y, fmaf(t1, q2.z, fmaf(t2, q2.w, db.y)));
            bool pass = (tmin >= 0.0f) && (dena >= thr);
            if (__any(pass)) {
                float4 cc = *(const float4*)(sf + 896 + 4 * j);  // ds,iz0,iz1,iz2
                float idb = sf[1152 + j];
                // bit-exact numpy path (t's reused)
                bool in = !(t0 < 0.0f) && !(t1 < 0.0f) && !(t2 < 0.0f);
                float w0 = __fdiv_rn(t0, cc.x);
                float w1 = __fdiv_rn(t1, cc.x);
                float w2 = __fdiv_rn(t2, cc.x);
                in = in && !(w0 > 1.0f) && !(w1 > 1.0f) && !(w2 > 1.0f);
                float den = __fmul_rn(w0, cc.y);
                den = __fadd_rn(den, __fmul_rn(w1, cc.z));
                den = __fadd_rn(den, __fmul_rn(w2, cc.w));
                if (in && den > 1e-8f) {
                    float zp = __fdiv_rn(1.0f, den);
                    if (zp > 0.1f && zp < 100.0f) {
                        u64 key = ((u64)__float_as_uint(zp) << 32)
                                | (u64)(unsigned)__float_as_int(idb);
                        if (key < best) {
                            best = key;
                            float b2f = __uint_as_float((unsigned)(best >> 32));
                            thr = fmaxf(thr,
                                0.9935f * __builtin_amdgcn_rcpf(b2f) - 1e-4f);
                        }
                    }
                }
            }
        }
        if (best != FARKEY)
            atomicMin(&keys[pix], best);
        if (!hasnext) return;
        c = cn;
    }
}

// ---------------------------------------------------------------------------
// Kernel 5: per-pixel epilogue — recompute the winner face's constants from
// the raw inputs (bit-exact prep replica), exact barycentrics, then
// trilinear-sample the face texture (numpy op order).
// ---------------------------------------------------------------------------
__global__ __launch_bounds__(256) void epilogue(
    const u64* __restrict__ keys,
    const float* __restrict__ cam,
    const float* __restrict__ verts,
    const int* __restrict__ faces,
    const float* __restrict__ tex,   // d_out + IMGOFF, from prep
    float* __restrict__ out_img)
{
    int pix = blockIdx.x * 256 + threadIdx.x;   // 65536
    int xo = pix & 255, yo = pix >> 8;
    const float xp = (float)(2 * xo + 1 - 256) * (1.0f / 256.0f);
    const float yp = (float)(2 * yo + 1 - 256) * (1.0f / 256.0f);
    u64 m = keys[pix];
    float depth = __uint_as_float((unsigned)(m >> 32));
    float col0 = 0.f, col1 = 0.f, col2 = 0.f;
    if (depth < 100.0f) {
        int fidx = (int)(unsigned)(m & 0xFFFFFFFFu);
        float c0 = cam[0], c1 = cam[1], c2 = cam[2];
        float z3 = __fdiv_rn(EYEZ, __fsqrt_rn(__fmul_rn(EYEZ, EYEZ)));
        float x0r = __fdiv_rn(z3, __fsqrt_rn(__fmul_rn(z3, z3)));
        float wyy = __fmul_rn(z3, x0r);
        float y1r = __fdiv_rn(wyy, __fsqrt_rn(__fmul_rn(wyy, wyy)));
        float xs[3], ys[3], zs[3];
#pragma unroll
        for (int i = 0; i < 3; i++) {
            int vi = faces[fidx * 3 + i];
            float vx = verts[vi * 3 + 0];
            float vy = verts[vi * 3 + 1];
            float vz = verts[vi * 3 + 2];
            float px = __fmul_rn(c0, __fadd_rn(vx, c1));
            float py = __fmul_rn(c0, __fadd_rn(vy, c2));
            xs[i] = __fmul_rn(px, x0r);
            ys[i] = __fmul_rn(-py, y1r);
            zs[i] = __fmul_rn(__fadd_rn(vz, EYEZ), z3);
        }
        float a0 = __fsub_rn(ys[1], ys[2]);
        float a1 = __fsub_rn(ys[2], ys[0]);
        float a2 = __fsub_rn(ys[0], ys[1]);
        float b0 = __fsub_rn(xs[2], xs[1]);
        float b1 = __fsub_rn(xs[0], xs[2]);
        float b2 = __fsub_rn(xs[1], xs[0]);
        float cc0 = __fsub_rn(__fmul_rn(xs[1], ys[2]), __fmul_rn(xs[2], ys[1]));
        float cc1 = __fsub_rn(__fmul_rn(xs[2], ys[0]), __fmul_rn(xs[0], ys[2]));
        float cc2 = __fsub_rn(__fmul_rn(xs[0], ys[1]), __fmul_rn(xs[1], ys[0]));
        float det = __fadd_rn(__fadd_rn(cc0, cc1), cc2);
        float dsf = (fabsf(det) > 1e-10f) ? det : 1e-10f;
        float z0 = (fabsf(zs[0]) > 1e-6f) ? zs[0] : 1e-6f;
        float z1 = (fabsf(zs[1]) > 1e-6f) ? zs[1] : 1e-6f;
        float z2 = (fabsf(zs[2]) > 1e-6f) ? zs[2] : 1e-6f;

        float t0 = __fadd_rn(__fadd_rn(__fmul_rn(xp, a0), __fmul_rn(yp, b0)), cc0);
        float t1 = __fadd_rn(__fadd_rn(__fmul_rn(xp, a1), __fmul_rn(yp, b1)), cc1);
        float t2 = __fadd_rn(__fadd_rn(__fmul_rn(xp, a2), __fmul_rn(yp, b2)), cc2);
        float w0 = __fdiv_rn(t0, dsf), w1 = __fdiv_rn(t1, dsf), w2 = __fdiv_rn(t2, dsf);
        float wc0 = __fdiv_rn(w0, z0);
        float wc1 = __fdiv_rn(w1, z1);
        float wc2 = __fdiv_rn(w2, z2);
        float ssum = __fadd_rn(__fadd_rn(wc0, wc1), wc2);
        float dnm = fmaxf(ssum, 1e-8f);
        wc0 = __fdiv_rn(wc0, dnm); wc1 = __fdiv_rn(wc1, dnm); wc2 = __fdiv_rn(wc2, dnm);
        float pos0 = __fmul_rn(fminf(fmaxf(wc0, 0.f), 1.f), 2.0f);
        float pos1 = __fmul_rn(fminf(fmaxf(wc1, 0.f), 1.f), 2.0f);
        float pos2 = __fmul_rn(fminf(fmaxf(wc2, 0.f), 1.f), 2.0f);
        float lf0 = fminf(fmaxf(floorf(pos0), 0.f), 2.f);
        float lf1 = fminf(fmaxf(floorf(pos1), 0.f), 2.f);
        float lf2 = fminf(fmaxf(floorf(pos2), 0.f), 2.f);
        float fr0 = __fsub_rn(pos0, lf0), fr1 = __fsub_rn(pos1, lf1), fr2 = __fsub_rn(pos2, lf2);
        int lo0 = (int)lf0, lo1 = (int)lf1;
        int hi0 = lo0 + 1 > 2 ? 2 : lo0 + 1;
        int hi1 = lo1 + 1 > 2 ? 2 : lo1 + 1;
        const float* tbase = tex + (size_t)fidx * 81;
#pragma unroll
        for (int bits = 0; bits < 8; bits++) {
            int u0 = bits & 1, u1 = (bits >> 1) & 1, u2 = (bits >> 2) & 1;
            int i0 = u0 ? hi0 : lo0;
            int i1 = u1 ? hi1 : lo1;
            float e0 = u0 ? fr0 : __fsub_rn(1.0f, fr0);
            float e1 = u1 ? fr1 : __fsub_rn(1.0f, fr1);
            float e2 = u2 ? fr2 : __fsub_rn(1.0f, fr2);
            float wgt = __fmul_rn(__fmul_rn(e0, e1), e2);
            const float* tp = tbase + (size_t)i0 * 27 + (size_t)i1 * 9;  // k broadcast
            col0 = __fadd_rn(col0, __fmul_rn(wgt, tp[0]));
            col1 = __fadd_rn(col1, __fmul_rn(wgt, tp[1]));
            col2 = __fadd_rn(col2, __fmul_rn(wgt, tp[2]));
        }
    }
    out_img[pix]          = col0;
    out_img[65536 + pix]  = col1;
    out_img[131072 + pix] = col2;
}

extern "C" void kernel_launch(void* const* d_in, const int* in_sizes, int n_in,
                              void* d_out, int out_size, void* d_ws, size_t ws_size,
                              hipStream_t stream) {
    const float* cam   = (const float*)d_in[0];
    const float* verts = (const float*)d_in[1];
    const float* uv    = (const float*)d_in[2];
    const int*   faces = (const int*)d_in[3];
    float* out = (float*)d_out;

    char* ws = (char*)d_ws;
    u64*    keys  = (u64*)(ws + OFF_KEYS);
    int*    qtot  = (int*)(ws + OFF_QTOT);
    int*    fcnt  = (int*)(ws + OFF_FCNT);
    int*    cntp  = (int*)(ws + OFF_CNT);
    int4*   cmeta = (int4*)(ws + OFF_CMETA);
    float*  cf    = (float*)(ws + OFF_CF);
    float4* cbb   = (float4*)(ws + OFF_CBB);
    int*    list  = (int*)(ws + OFF_LIST);

    int cap = CAPMAX;
    if (ws_size > OFF_LIST) {
        size_t avail = (ws_size - OFF_LIST) / (1024 * sizeof(int));
        if ((size_t)cap > avail) cap = (int)avail;
    } else {
        cap = 0;
    }

    float* out_img = out;            // 3*256*256
    float* out_tex = out + IMGOFF;   // NF*81

    // zero fcnt + per-tile cnt (graph-capture-safe async memset)
    hipMemsetAsync(ws + OFF_QTOT, 0, (OFF_CNT + 4096) - OFF_QTOT, stream);

    hipLaunchKernelGGL(prep, dim3((NF * 9 + 255) / 256), dim3(256), 0, stream,
                       cam, verts, faces, uv, keys, cf, cbb, fcnt, out_tex);
    hipLaunchKernelGGL(bin_faces, dim3(1728), dim3(256), 0, stream,
                       cf, cbb, fcnt, cntp, list, cap);
    hipLaunchKernelGGL(prefix_chunks, dim3(1), dim3(1024), 0, stream,
                       cntp, cap, cmeta, qtot);
    hipLaunchKernelGGL(raster_score, dim3(NWAVES / 4), dim3(256), 0, stream,
                       cf, list, cmeta, qtot, keys);
    hipLaunchKernelGGL(epilogue, dim3(256), dim3(256), 0, stream,
                       keys, cam, verts, faces, out_tex, out_img);
}